// Round 6
// baseline (149.450 us; speedup 1.0000x reference)
//
#include <hip/hip_runtime.h>
#include <hip/hip_bf16.h>

#define BB 8
#define SS 4096
#define DD 1024
#define KK 32
#define EE 8
#define PP 4

// ---- output float offsets (tuple concatenated flat, in return order) ----
#define O0 0L                    // expert_weights  (B,S,E)   262144
#define O1 262144L               // expert_indices  (B,S,E)   262144
#define O2 524288L               // phi_weights     (B,S,K)  1048576
#define O3 1572864L              // soft_slots      (B,K*D)   262144
#define O4 1835008L              // expert_inputs   (B,K*D)   262144
#define O5 2097152L              // phi_logits      (B,S,K)  1048576
#define O6 3145728L              // raw_gate_probs  (B,S,K)  1048576

// ---- workspace float offsets ----
#define WA 0L        // softmax partials: 128 blocks * 64 floats
#define WB 8192L     // final m / (1/sum) per (b,k): 8*64 floats
#define WC 16384L    // logits d-quarter partials (16.8MB) THEN k_slots partials

// ============ K1 v5: logits partial GEMM, 2048 blocks for occupancy =======
// Grid 2048 = 512 token-tiles(64 tok) x 4 d-quarters(256 d). Block = 4 waves,
// wave wv owns k-slice [8wv,8wv+8). 4 chunks of 64 d, single LDS buffer
// (25.6KB -> 6 blocks/CU = 75% occ) + register prefetch of next chunk.
// Writes partial [q][tok][32k] to ws (no bias). Epilogue lives in k_comb2.
__global__ __launch_bounds__(256) void k_logits5(const float* __restrict__ x,
    const float* __restrict__ Wp, float* __restrict__ wsP)
{
    __shared__ float xl[64][68];       // 17408 B  (pad 4: b128-friendly)
    __shared__ float wl[64][32];       // 8192 B
    const int tid  = threadIdx.x;
    const int wv   = __builtin_amdgcn_readfirstlane(tid >> 6);
    const int lane = tid & 63;
    const int blk  = blockIdx.x;
    const int tile = blk >> 2, q = blk & 3;
    const long tok0 = (long)tile * 64;
    const int d0 = q * 256;
    const int sr  = tid >> 2;           // stage row 0..63
    const int sco = (tid & 3) * 4;      // stage col quad base (16B)

    float acc[8];
#pragma unroll
    for (int j = 0; j < 8; ++j) acc[j] = 0.f;

    float4 xr[4], wr[2];
    // preload + stage chunk 0
#pragma unroll
    for (int j = 0; j < 4; ++j)
        xr[j] = *reinterpret_cast<const float4*>(x + (tok0 + sr) * DD + d0 + sco + j * 16);
#pragma unroll
    for (int j = 0; j < 2; ++j)
        wr[j] = *reinterpret_cast<const float4*>(Wp + (long)d0 * KK + tid * 8 + j * 4);
#pragma unroll
    for (int j = 0; j < 4; ++j)
        *reinterpret_cast<float4*>(&xl[sr][sco + j * 16]) = xr[j];
#pragma unroll
    for (int j = 0; j < 2; ++j)
        *reinterpret_cast<float4*>(&wl[0][0] + tid * 8 + j * 4) = wr[j];
    __syncthreads();

    for (int c = 0; c < 4; ++c) {
        if (c < 3) {                    // prefetch next chunk into registers
            const long db = (long)d0 + (c + 1) * 64;
#pragma unroll
            for (int j = 0; j < 4; ++j)
                xr[j] = *reinterpret_cast<const float4*>(
                    x + (tok0 + sr) * DD + db + sco + j * 16);
#pragma unroll
            for (int j = 0; j < 2; ++j)
                wr[j] = *reinterpret_cast<const float4*>(
                    Wp + db * KK + tid * 8 + j * 4);
        }
        const float* xb = &xl[lane][0];
        const float* wb = &wl[0][0] + wv * 8;
#pragma unroll 4
        for (int dq = 0; dq < 16; ++dq) {
            const float4 xv = *reinterpret_cast<const float4*>(xb + dq * 4);
#pragma unroll
            for (int dd = 0; dd < 4; ++dd) {
                const float xs = (dd == 0) ? xv.x : (dd == 1) ? xv.y
                               : (dd == 2) ? xv.z : xv.w;
                const float4 w0 = *reinterpret_cast<const float4*>(wb + (dq * 4 + dd) * 32);
                const float4 w1 = *reinterpret_cast<const float4*>(wb + (dq * 4 + dd) * 32 + 4);
                acc[0] = fmaf(xs, w0.x, acc[0]);
                acc[1] = fmaf(xs, w0.y, acc[1]);
                acc[2] = fmaf(xs, w0.z, acc[2]);
                acc[3] = fmaf(xs, w0.w, acc[3]);
                acc[4] = fmaf(xs, w1.x, acc[4]);
                acc[5] = fmaf(xs, w1.y, acc[5]);
                acc[6] = fmaf(xs, w1.z, acc[6]);
                acc[7] = fmaf(xs, w1.w, acc[7]);
            }
        }
        __syncthreads();                // all waves done reading LDS
        if (c < 3) {
#pragma unroll
            for (int j = 0; j < 4; ++j)
                *reinterpret_cast<float4*>(&xl[sr][sco + j * 16]) = xr[j];
#pragma unroll
            for (int j = 0; j < 2; ++j)
                *reinterpret_cast<float4*>(&wl[0][0] + tid * 8 + j * 4) = wr[j];
            __syncthreads();
        }
    }

    // partial out: wsP[q][tok][k]
    float* o = wsP + ((long)q * 32768 + tok0 + lane) * KK + wv * 8;
    *reinterpret_cast<float4*>(o)     = make_float4(acc[0], acc[1], acc[2], acc[3]);
    *reinterpret_cast<float4*>(o + 4) = make_float4(acc[4], acc[5], acc[6], acc[7]);
}

// ============ K1b v2: combine 4 partials + bias + epilogue + sm stats ======
// 128 blocks x 256 thr; thread = one token. Also does k_smpart's job.
__global__ __launch_bounds__(256) void k_comb2(const float* __restrict__ wsP,
    const float* __restrict__ bp, float* __restrict__ out, float* __restrict__ ws)
{
    const int blk = blockIdx.x;            // = b*16 + sc (256-token chunk)
    const int tid = threadIdx.x;
    const int wv  = __builtin_amdgcn_readfirstlane(tid >> 6);
    const long g  = (long)blk * 256 + tid;
    float acc[KK];
#pragma unroll
    for (int k = 0; k < KK; ++k) acc[k] = bp[k];
#pragma unroll
    for (int q = 0; q < 4; ++q) {
        const float4* p = reinterpret_cast<const float4*>(wsP + ((long)q * 32768 + g) * KK);
#pragma unroll
        for (int j = 0; j < 8; ++j) {
            const float4 v = p[j];
            acc[4*j]   += v.x;
            acc[4*j+1] += v.y;
            acc[4*j+2] += v.z;
            acc[4*j+3] += v.w;
        }
    }
    float4* pl = reinterpret_cast<float4*>(out + O5 + g * KK);
#pragma unroll
    for (int j = 0; j < 8; ++j)
        pl[j] = make_float4(acc[4*j], acc[4*j+1], acc[4*j+2], acc[4*j+3]);
    // raw gate probs (softmax over P=4 within each expert)
    float rg[KK];
#pragma unroll
    for (int e = 0; e < EE; ++e) {
        const float m = fmaxf(fmaxf(acc[4*e], acc[4*e+1]), fmaxf(acc[4*e+2], acc[4*e+3]));
        float s = 0.f;
#pragma unroll
        for (int p = 0; p < PP; ++p) { rg[4*e+p] = __expf(acc[4*e+p] - m); s += rg[4*e+p]; }
        const float ri = 1.f / s;
#pragma unroll
        for (int p = 0; p < PP; ++p) rg[4*e+p] *= ri;
    }
    float4* prg = reinterpret_cast<float4*>(out + O6 + g * KK);
#pragma unroll
    for (int j = 0; j < 8; ++j)
        prg[j] = make_float4(rg[4*j], rg[4*j+1], rg[4*j+2], rg[4*j+3]);
    float4* pew = reinterpret_cast<float4*>(out + O0 + g * EE);
    pew[0] = make_float4(0.125f, 0.125f, 0.125f, 0.125f);
    pew[1] = make_float4(0.125f, 0.125f, 0.125f, 0.125f);
    float4* pei = reinterpret_cast<float4*>(out + O1 + g * EE);
    pei[0] = make_float4(0.f, 1.f, 2.f, 3.f);
    pei[1] = make_float4(4.f, 5.f, 6.f, 7.f);

    // ---- seq-softmax partial stats over this 256-token chunk ----
    float m[KK];
#pragma unroll
    for (int k = 0; k < KK; ++k) m[k] = acc[k];
    for (int off = 1; off < 64; off <<= 1) {
#pragma unroll
        for (int k = 0; k < KK; ++k) m[k] = fmaxf(m[k], __shfl_xor(m[k], off));
    }
    __shared__ float lm[4][KK];
    __shared__ float lsum[4][KK];
    if ((tid & 63) == 0) {
#pragma unroll
        for (int k = 0; k < KK; ++k) lm[wv][k] = m[k];
    }
    __syncthreads();
#pragma unroll
    for (int k = 0; k < KK; ++k)
        m[k] = fmaxf(fmaxf(lm[0][k], lm[1][k]), fmaxf(lm[2][k], lm[3][k]));
    float sv[KK];
#pragma unroll
    for (int k = 0; k < KK; ++k) sv[k] = __expf(acc[k] - m[k]);
    for (int off = 1; off < 64; off <<= 1) {
#pragma unroll
        for (int k = 0; k < KK; ++k) sv[k] += __shfl_xor(sv[k], off);
    }
    if ((tid & 63) == 0) {
#pragma unroll
        for (int k = 0; k < KK; ++k) lsum[wv][k] = sv[k];
    }
    __syncthreads();
    if (tid == 0) {
#pragma unroll
        for (int k = 0; k < KK; ++k) {
            ws[WA + (long)blk * 64 + k]      = m[k];
            ws[WA + (long)blk * 64 + 32 + k] = lsum[0][k] + lsum[1][k] + lsum[2][k] + lsum[3][k];
        }
    }
}

// ============ K1 fallback (v4 direct) + stats kernel, if ws is tiny ========
__global__ __launch_bounds__(256) void k_logits4(const float* __restrict__ x,
    const float* __restrict__ Wp, const float* __restrict__ bp,
    float* __restrict__ out)
{
    __shared__ float xl[2][64][68];
    __shared__ float wl[2][64][32];
    const int tid  = threadIdx.x;
    const int wv   = __builtin_amdgcn_readfirstlane(tid >> 6);
    const int lane = tid & 63;
    const long tok0 = (long)blockIdx.x * 64;
    const long g   = tok0 + lane;
    const int sr = tid >> 2;
    const int sco = (tid & 3) * 4;
    float acc[8];
#pragma unroll
    for (int j = 0; j < 8; ++j) acc[j] = 0.f;
    float4 xr[4], wr[2];
#pragma unroll
    for (int j = 0; j < 4; ++j)
        xr[j] = *reinterpret_cast<const float4*>(x + (tok0 + sr) * DD + sco + j * 16);
#pragma unroll
    for (int j = 0; j < 2; ++j)
        wr[j] = *reinterpret_cast<const float4*>(Wp + tid * 8 + j * 4);
#pragma unroll
    for (int j = 0; j < 4; ++j)
        *reinterpret_cast<float4*>(&xl[0][sr][sco + j * 16]) = xr[j];
#pragma unroll
    for (int j = 0; j < 2; ++j)
        *reinterpret_cast<float4*>(&wl[0][0][0] + tid * 8 + j * 4) = wr[j];
    __syncthreads();
    for (int c = 0; c < 16; ++c) {
        const int cb = c & 1;
        if (c < 15) {
            const long dg = (long)(c + 1) * 64;
#pragma unroll
            for (int j = 0; j < 4; ++j)
                xr[j] = *reinterpret_cast<const float4*>(
                    x + (tok0 + sr) * DD + dg + sco + j * 16);
#pragma unroll
            for (int j = 0; j < 2; ++j)
                wr[j] = *reinterpret_cast<const float4*>(Wp + dg * KK + tid * 8 + j * 4);
        }
        const float* xb = &xl[cb][lane][0];
        const float* wb = &wl[cb][0][0] + wv * 8;
#pragma unroll 4
        for (int dq = 0; dq < 16; ++dq) {
            const float4 xv = *reinterpret_cast<const float4*>(xb + dq * 4);
#pragma unroll
            for (int dd = 0; dd < 4; ++dd) {
                const float xs = (dd == 0) ? xv.x : (dd == 1) ? xv.y
                               : (dd == 2) ? xv.z : xv.w;
                const float4 w0 = *reinterpret_cast<const float4*>(wb + (dq * 4 + dd) * 32);
                const float4 w1 = *reinterpret_cast<const float4*>(wb + (dq * 4 + dd) * 32 + 4);
                acc[0] = fmaf(xs, w0.x, acc[0]);
                acc[1] = fmaf(xs, w0.y, acc[1]);
                acc[2] = fmaf(xs, w0.z, acc[2]);
                acc[3] = fmaf(xs, w0.w, acc[3]);
                acc[4] = fmaf(xs, w1.x, acc[4]);
                acc[5] = fmaf(xs, w1.y, acc[5]);
                acc[6] = fmaf(xs, w1.z, acc[6]);
                acc[7] = fmaf(xs, w1.w, acc[7]);
            }
        }
        if (c < 15) {
#pragma unroll
            for (int j = 0; j < 4; ++j)
                *reinterpret_cast<float4*>(&xl[cb ^ 1][sr][sco + j * 16]) = xr[j];
#pragma unroll
            for (int j = 0; j < 2; ++j)
                *reinterpret_cast<float4*>(&wl[cb ^ 1][0][0] + tid * 8 + j * 4) = wr[j];
        }
        __syncthreads();
    }
#pragma unroll
    for (int j = 0; j < 8; ++j) acc[j] += bp[wv * 8 + j];
    float* o5 = out + O5 + g * KK + wv * 8;
    *reinterpret_cast<float4*>(o5)     = make_float4(acc[0], acc[1], acc[2], acc[3]);
    *reinterpret_cast<float4*>(o5 + 4) = make_float4(acc[4], acc[5], acc[6], acc[7]);
    float rg[8];
#pragma unroll
    for (int e = 0; e < 2; ++e) {
        const float* a = &acc[e * 4];
        const float m = fmaxf(fmaxf(a[0], a[1]), fmaxf(a[2], a[3]));
        float s = 0.f;
#pragma unroll
        for (int p = 0; p < PP; ++p) { rg[e*4+p] = __expf(a[p] - m); s += rg[e*4+p]; }
        const float ri = 1.f / s;
#pragma unroll
        for (int p = 0; p < PP; ++p) rg[e*4+p] *= ri;
    }
    float* o6 = out + O6 + g * KK + wv * 8;
    *reinterpret_cast<float4*>(o6)     = make_float4(rg[0], rg[1], rg[2], rg[3]);
    *reinterpret_cast<float4*>(o6 + 4) = make_float4(rg[4], rg[5], rg[6], rg[7]);
    if (wv == 0) {
        float4* p = reinterpret_cast<float4*>(out + O0 + g * EE);
        p[0] = make_float4(0.125f, 0.125f, 0.125f, 0.125f);
        p[1] = make_float4(0.125f, 0.125f, 0.125f, 0.125f);
    } else if (wv == 1) {
        float4* p = reinterpret_cast<float4*>(out + O1 + g * EE);
        p[0] = make_float4(0.f, 1.f, 2.f, 3.f);
        p[1] = make_float4(4.f, 5.f, 6.f, 7.f);
    }
}

__global__ __launch_bounds__(256) void k_smpart(const float* __restrict__ out,
                                                float* __restrict__ ws)
{
    const int blk = blockIdx.x;
    const int tid = threadIdx.x;
    const int wv  = __builtin_amdgcn_readfirstlane(tid >> 6);
    const int b = blk >> 4, sc = blk & 15;
    const long s  = (long)sc * 256 + tid;
    const float* row = out + O5 + ((long)b * SS + s) * KK;
    float v[KK];
    const float4* r4 = reinterpret_cast<const float4*>(row);
#pragma unroll
    for (int q = 0; q < 8; ++q) {
        const float4 t = r4[q];
        v[4*q] = t.x; v[4*q+1] = t.y; v[4*q+2] = t.z; v[4*q+3] = t.w;
    }
    float m[KK];
#pragma unroll
    for (int k = 0; k < KK; ++k) m[k] = v[k];
    for (int off = 1; off < 64; off <<= 1) {
#pragma unroll
        for (int k = 0; k < KK; ++k) m[k] = fmaxf(m[k], __shfl_xor(m[k], off));
    }
    __shared__ float lm[4][KK];
    __shared__ float lsum[4][KK];
    if ((tid & 63) == 0) {
#pragma unroll
        for (int k = 0; k < KK; ++k) lm[wv][k] = m[k];
    }
    __syncthreads();
#pragma unroll
    for (int k = 0; k < KK; ++k)
        m[k] = fmaxf(fmaxf(lm[0][k], lm[1][k]), fmaxf(lm[2][k], lm[3][k]));
    float sv[KK];
#pragma unroll
    for (int k = 0; k < KK; ++k) sv[k] = __expf(v[k] - m[k]);
    for (int off = 1; off < 64; off <<= 1) {
#pragma unroll
        for (int k = 0; k < KK; ++k) sv[k] += __shfl_xor(sv[k], off);
    }
    if ((tid & 63) == 0) {
#pragma unroll
        for (int k = 0; k < KK; ++k) lsum[wv][k] = sv[k];
    }
    __syncthreads();
    if (tid == 0) {
#pragma unroll
        for (int k = 0; k < KK; ++k) {
            ws[WA + (long)blk * 64 + k]      = m[k];
            ws[WA + (long)blk * 64 + 32 + k] = lsum[0][k] + lsum[1][k] + lsum[2][k] + lsum[3][k];
        }
    }
}

// ============ K2b: combine 16 chunk stats -> final m, 1/sum per (b,k) ======
__global__ __launch_bounds__(256) void k_smcomb(float* __restrict__ ws)
{
    const int tid = threadIdx.x;           // = b*32 + k
    const int b = tid >> 5, k = tid & 31;
    float m = -1e30f, s = 0.f;
    for (int c = 0; c < 16; ++c) {
        const float mc = ws[WA + (long)(b * 16 + c) * 64 + k];
        const float sc = ws[WA + (long)(b * 16 + c) * 64 + 32 + k];
        const float nm = fmaxf(m, mc);
        s = s * __expf(m - nm) + sc * __expf(mc - nm);
        m = nm;
    }
    ws[WB + (long)b * 64 + k]      = m;
    ws[WB + (long)b * 64 + 32 + k] = 1.f / s;
}

// ============ K2c: phi_weights = exp(logit - m) * rinv ====================
__global__ __launch_bounds__(256) void k_pw(float* __restrict__ out,
                                            const float* __restrict__ ws)
{
    const long i4 = (long)blockIdx.x * 256 + threadIdx.x;   // < 262144
    const float4 l4 = reinterpret_cast<const float4*>(out + O5)[i4];
    const long idx = i4 * 4;
    const int b  = (int)(idx >> 17);
    const int k0 = (int)(idx & 31);
    const float* mb = ws + WB + (long)b * 64;
    const float lv[4] = {l4.x, l4.y, l4.z, l4.w};
    float r[4];
#pragma unroll
    for (int j = 0; j < 4; ++j) {
        const int k = k0 + j;
        r[j] = __expf(lv[j] - mb[k]) * mb[32 + k];
    }
    reinterpret_cast<float4*>(out + O2)[i4] = make_float4(r[0], r[1], r[2], r[3]);
}

// ============ K3 v2: soft_slots partials, pw staged in LDS ================
__global__ __launch_bounds__(256) void k_slots2(const float* __restrict__ x,
    const float* __restrict__ out, float* __restrict__ dst, int SC, int SLEN)
{
    __shared__ float pwl[2][64 * KK];
    const int tid = threadIdx.x;
    const int blk = blockIdx.x;
    const int sc  = blk % SC;
    const int t2  = blk / SC;
    const int dc  = t2 & 3;
    const int b   = t2 >> 2;
    const int d   = dc * 256 + tid;
    float acc[KK];
#pragma unroll
    for (int k = 0; k < KK; ++k) acc[k] = 0.f;
    const long s0 = (long)sc * SLEN;
    const float* pw = out + O2 + ((long)b * SS + s0) * KK;
    const float* xp = x + ((long)b * SS + s0) * DD + d;
    const int NCH = SLEN >> 6;

    float4 r0 = *reinterpret_cast<const float4*>(pw + tid * 8);
    float4 r1 = *reinterpret_cast<const float4*>(pw + tid * 8 + 4);
    *reinterpret_cast<float4*>(&pwl[0][tid * 8])     = r0;
    *reinterpret_cast<float4*>(&pwl[0][tid * 8 + 4]) = r1;
    __syncthreads();

    for (int ch = 0; ch < NCH; ++ch) {
        const int cb = ch & 1;
        if (ch + 1 < NCH) {
            const float* pn = pw + (long)(ch + 1) * 64 * KK;
            r0 = *reinterpret_cast<const float4*>(pn + tid * 8);
            r1 = *reinterpret_cast<const float4*>(pn + tid * 8 + 4);
        }
        const float* xc = xp + (long)ch * 64 * DD;
        const float* pb = &pwl[cb][0];
#pragma unroll 8
        for (int i = 0; i < 64; ++i) {
            const float xv = xc[(long)i * DD];
#pragma unroll
            for (int q = 0; q < 8; ++q) {
                const float4 w = *reinterpret_cast<const float4*>(pb + i * KK + q * 4);
                acc[4*q]   = fmaf(w.x, xv, acc[4*q]);
                acc[4*q+1] = fmaf(w.y, xv, acc[4*q+1]);
                acc[4*q+2] = fmaf(w.z, xv, acc[4*q+2]);
                acc[4*q+3] = fmaf(w.w, xv, acc[4*q+3]);
            }
        }
        if (ch + 1 < NCH) {
            *reinterpret_cast<float4*>(&pwl[cb ^ 1][tid * 8])     = r0;
            *reinterpret_cast<float4*>(&pwl[cb ^ 1][tid * 8 + 4]) = r1;
        }
        __syncthreads();
    }
    float* o = dst + ((long)(sc * BB + b) * KK) * DD + d;
#pragma unroll
    for (int k = 0; k < KK; ++k) o[(long)k * DD] = acc[k];
}

// ============ K4: reduce SC partials -> soft_slots + expert_inputs =========
__global__ __launch_bounds__(256) void k_red(const float* __restrict__ src,
                                             float* __restrict__ out, int SC)
{
    const long i4 = (long)blockIdx.x * 256 + threadIdx.x;   // < 65536
    float4 s = make_float4(0.f, 0.f, 0.f, 0.f);
    const float4* p = reinterpret_cast<const float4*>(src);
    for (int c = 0; c < SC; ++c) {
        const float4 t = p[(long)c * 65536 + i4];
        s.x += t.x; s.y += t.y; s.z += t.z; s.w += t.w;
    }
    reinterpret_cast<float4*>(out + O3)[i4] = s;
    reinterpret_cast<float4*>(out + O4)[i4] = s;
}

extern "C" void kernel_launch(void* const* d_in, const int* in_sizes, int n_in,
                              void* d_out, int out_size, void* d_ws, size_t ws_size,
                              hipStream_t stream)
{
    const float* x  = (const float*)d_in[0];
    const float* Wp = (const float*)d_in[1];
    const float* bp = (const float*)d_in[2];
    float* out = (float*)d_out;
    float* ws  = (float*)d_ws;

    const size_t wfloats = ws_size / 4;
    const long wsP_floats = 4L * 32768 * 32;   // 4.19M floats = 16.8 MB

    // ---- logits ----
    if (wfloats >= (size_t)(WC + wsP_floats)) {
        hipLaunchKernelGGL(k_logits5, dim3(2048), dim3(256), 0, stream, x, Wp, ws + WC);
        hipLaunchKernelGGL(k_comb2,   dim3(128),  dim3(256), 0, stream, ws + WC, bp, out, ws);
    } else {
        hipLaunchKernelGGL(k_logits4, dim3(512), dim3(256), 0, stream, x, Wp, bp, out);
        hipLaunchKernelGGL(k_smpart,  dim3(128), dim3(256), 0, stream, out, ws);
    }

    hipLaunchKernelGGL(k_smcomb, dim3(1),    dim3(256), 0, stream, ws);
    hipLaunchKernelGGL(k_pw,     dim3(1024), dim3(256), 0, stream, out, ws);

    // ---- soft slots (WC region reused after k_comb2 consumed wsP) ----
    int SC = 0;
    if      (wfloats >= (size_t)(WC + 32L * 262144)) SC = 32;
    else if (wfloats >= (size_t)(WC + 16L * 262144)) SC = 16;
    else if (wfloats >= (size_t)(WC +  8L * 262144)) SC = 8;
    else if (wfloats >= (size_t)(WC +  4L * 262144)) SC = 4;
    else if (wfloats >= (size_t)(WC +  2L * 262144)) SC = 2;
    else if (wfloats >= (size_t)(WC +  1L * 262144)) SC = 1;

    if (SC >= 1) {
        hipLaunchKernelGGL(k_slots2, dim3(BB * 4 * SC), dim3(256), 0, stream,
                           x, out, ws + WC, SC, SS / SC);
        hipLaunchKernelGGL(k_red,    dim3(256), dim3(256), 0, stream, ws + WC, out, SC);
    } else {
        hipLaunchKernelGGL(k_slots2, dim3(BB * 4), dim3(256), 0, stream,
                           x, out, out + O3, 1, SS);
        hipLaunchKernelGGL(k_red,    dim3(256), dim3(256), 0, stream, out + O3, out, 1);
    }
}